// Round 3
// baseline (194.394 us; speedup 1.0000x reference)
//
#include <hip/hip_runtime.h>
#include <math.h>

// Problem constants (fixed by setup_inputs)
#define NB 16
#define NT 4096
#define NC 64
#define NS 5
#define NH 32

#define TTILE 64
#define RMX 56
#define PN (TTILE + 2*RMX)   // 176 staged t-positions per tile

// tap table segment offsets: radii {10,16,24,36,56} -> lengths {21,33,49,73,113}
#define OFF0 0
#define OFF1 21
#define OFF2 54
#define OFF3 103
#define OFF4 176
#define NTAPS 289

#define NFRAG 13            // K-steps total: 2+2+2+3+4
#define SXT_LD 184          // bf16 elements per channel row (16B-aligned reads, 2-way banks)
#define SXS_LD 92           // f32 stride for transposed stats array (2-way banks)

// MLP weight-table (z, logvar) -> 4 softmax weights (5th = 1 - sum)
#define NZ 512
#define NV 256
#define ZMINF (-4.0f)
#define VMINF (-14.0f)
#define ZSCLF (511.0f / 8.0f)     // (NZ-1)/(ZMAX-ZMIN)
#define VSCLF (255.0f / 18.0f)    // (NV-1)/(VMAX-VMIN)
#define FRAG_BYTES 16384
#define TABLE_BYTES ((size_t)NZ * NV * 16)
#define WS_NEED (FRAG_BYTES + TABLE_BYTES)

typedef __attribute__((ext_vector_type(8))) short bf16x8;
typedef __attribute__((ext_vector_type(4))) float f32x4;

__device__ __forceinline__ unsigned short f2b(float f) {
    unsigned int u = __float_as_uint(f);
    unsigned int r = (u + 0x7fffu + ((u >> 16) & 1u)) >> 16;   // RNE
    return (unsigned short)r;
}
__device__ __forceinline__ float hlo(unsigned int u) {
    union { unsigned int u_; _Float16 h[2]; } t; t.u_ = u; return (float)t.h[0];
}
__device__ __forceinline__ float hhi(unsigned int u) {
    union { unsigned int u_; _Float16 h[2]; } t; t.u_ = u; return (float)t.h[1];
}
__device__ __forceinline__ unsigned int packh2(float a, float b) {
    union { unsigned int u_; _Float16 h[2]; } t;
    t.h[0] = (_Float16)a; t.h[1] = (_Float16)b; return t.u_;
}

// exact MLP + softmax (cold path + table build)
__device__ __attribute__((noinline)) void mlp_w(
    float z, float lv,
    const float* __restrict__ W1, const float* __restrict__ b1,
    const float* __restrict__ W2, const float* __restrict__ b2,
    float* __restrict__ wout)
{
    float l0 = b2[0], l1 = b2[1], l2 = b2[2], l3 = b2[3], l4 = b2[4];
    #pragma unroll 1
    for (int j = 0; j < NH; ++j) {
        const float a = fmaf(z, W1[2 * j], fmaf(lv, W1[2 * j + 1], b1[j]));
        const float g = 0.5f * a * (1.0f + erff(a * 0.70710678118654752f));
        l0 = fmaf(g, W2[j],          l0);
        l1 = fmaf(g, W2[NH + j],     l1);
        l2 = fmaf(g, W2[2 * NH + j], l2);
        l3 = fmaf(g, W2[3 * NH + j], l3);
        l4 = fmaf(g, W2[4 * NH + j], l4);
    }
    const float sc = 1.4285714285714286f;
    const float mx = fmaxf(fmaxf(fmaxf(l0, l1), fmaxf(l2, l3)), l4);
    const float e0 = expf((l0 - mx) * sc);
    const float e1 = expf((l1 - mx) * sc);
    const float e2 = expf((l2 - mx) * sc);
    const float e3 = expf((l3 - mx) * sc);
    const float e4 = expf((l4 - mx) * sc);
    const float rd = 1.0f / (e0 + e1 + e2 + e3 + e4);
    wout[0] = e0 * rd; wout[1] = e1 * rd; wout[2] = e2 * rd;
    wout[3] = e3 * rd; wout[4] = e4 * rd;
}

// ---------------- init: normalized taps -> MFMA A-fragments in d_ws ----------------
__global__ void init_frags_kernel(unsigned short* __restrict__ afr) {
    __shared__ float raw[NTAPS];
    __shared__ float invs[NS];
    const int offs[6] = {OFF0, OFF1, OFF2, OFF3, OFF4, NTAPS};
    const float sig[NS] = {2.5f, 4.0f, 6.0f, 9.0f, 14.0f};
    const int RR[NS] = {10, 16, 24, 36, 56};
    const int tid = threadIdx.x;
    for (int i = tid; i < NTAPS; i += blockDim.x) {
        int s = 0;
        #pragma unroll
        for (int k = 1; k < NS; ++k) if (i >= offs[k]) s = k;
        const int j = i - offs[s] - RR[s];
        const float u = (float)j / sig[s];
        raw[i] = expf(-0.5f * u * u);
    }
    __syncthreads();
    if (tid < NS) {
        float sum = 0.f;
        for (int i = offs[tid]; i < offs[tid + 1]; ++i) sum += raw[i];
        invs[tid] = 1.0f / (sum + 1e-12f);
    }
    __syncthreads();
    const int fbase6[6] = {0, 2, 4, 6, 9, 13};
    const int RA[NS] = {16, 16, 24, 40, 56};
    for (int idx = tid; idx < NFRAG * 64 * 8; idx += blockDim.x) {
        const int f = idx >> 9;
        const int lane = (idx >> 3) & 63;
        const int e = idx & 7;
        int s = 0;
        #pragma unroll
        for (int k = 1; k < NS; ++k) if (f >= fbase6[k]) s = k;
        const int kk = f - fbase6[s];
        const int r = lane & 15;
        const int g = lane >> 4;
        const int j = 32 * kk + 8 * g + e - RA[s] - r;
        float v = 0.f;
        if (j >= -RR[s] && j <= RR[s]) v = raw[offs[s] + j + RR[s]] * invs[s];
        afr[idx] = f2b(v);
    }
}

// ---------------- build the (z, lv) -> weights table ----------------
// cell(zi,vi) = 16B: {w0..w3 fp16 @ vi | w0..w3 fp16 @ vi+1}
__global__ void build_table_kernel(
    const float* __restrict__ W1, const float* __restrict__ b1,
    const float* __restrict__ W2, const float* __restrict__ b2,
    unsigned int* __restrict__ tbl)
{
    const int idx = blockIdx.x * 256 + threadIdx.x;   // zi*NV + vi
    const int zi = idx / NV, vi = idx % NV;
    const float z  = ZMINF + (float)zi * (8.0f / 511.0f);
    const float lv = VMINF + (float)vi * (18.0f / 255.0f);
    float w[5];
    mlp_w(z, lv, W1, b1, W2, b2, w);
    const unsigned int p01 = packh2(w[0], w[1]);
    const unsigned int p23 = packh2(w[2], w[3]);
    uint2 p = {p01, p23};
    *reinterpret_cast<uint2*>(tbl + (size_t)idx * 4) = p;              // own lo
    if (vi > 0)
        *reinterpret_cast<uint2*>(tbl + (size_t)(idx - 1) * 4 + 2) = p; // left's hi
    if (vi == NV - 1)
        *reinterpret_cast<uint2*>(tbl + (size_t)idx * 4 + 2) = p;       // self hi (clamp)
}

// ---------------- fused main kernel ----------------
template<bool SLOW>
__global__ __launch_bounds__(256, 3) void fused3_kernel(
    const float* __restrict__ x,  const float* __restrict__ W1,
    const float* __restrict__ b1, const float* __restrict__ W2,
    const float* __restrict__ b2, const unsigned short* __restrict__ afr,
    const uint4* __restrict__ tb4, float* __restrict__ out)
{
    __shared__ __align__(16) short sxT[64 * SXT_LD];   // bf16 [c][t], 23552 B
    __shared__ __align__(16) float sxS[64 * SXS_LD];   // f32  [c][t], 23552 B

    const int blk = blockIdx.x;
    const int b  = blk >> 6;              // NT/TTILE = 64
    const int t0 = (blk & 63) * TTILE;
    const float* xb = x + (size_t)b * NT * NC;
    const int tid = threadIdx.x;

    // ---- stage sxT (bf16 [c][t], reflect-padded), 4-wide ds_write_b64 ----
    for (int idx = tid; idx < 44 * 16; idx += 256) {
        const int p4 = idx >> 4;
        const int c4 = (idx & 15) << 2;
        float vv[4][4];
        #pragma unroll
        for (int k = 0; k < 4; ++k) {
            int gg = t0 - RMX + 4 * p4 + k;
            if (gg < 0) gg = -gg;
            if (gg >= NT) gg = 2 * NT - 2 - gg;
            const float4 v = *reinterpret_cast<const float4*>(xb + (size_t)gg * NC + c4);
            vv[k][0] = v.x; vv[k][1] = v.y; vv[k][2] = v.z; vv[k][3] = v.w;
        }
        #pragma unroll
        for (int kc = 0; kc < 4; ++kc) {
            const unsigned int lo = (unsigned int)f2b(vv[0][kc]) | ((unsigned int)f2b(vv[1][kc]) << 16);
            const unsigned int hi = (unsigned int)f2b(vv[2][kc]) | ((unsigned int)f2b(vv[3][kc]) << 16);
            uint2 pw = {lo, hi};
            *reinterpret_cast<uint2*>(&sxT[(c4 + kc) * SXT_LD + 4 * p4]) = pw;
        }
    }
    // ---- stage sxS (f32 [c][t], replicate-left, rows t0-15 .. t0+64) ----
    for (int idx = tid; idx < 20 * 16; idx += 256) {
        const int p4 = idx >> 4;
        const int c4 = (idx & 15) << 2;
        float vv[4][4];
        #pragma unroll
        for (int k = 0; k < 4; ++k) {
            int gg = t0 - 15 + 4 * p4 + k;
            if (gg < 0) gg = 0;
            if (gg > NT - 1) gg = NT - 1;
            const float4 v = *reinterpret_cast<const float4*>(xb + (size_t)gg * NC + c4);
            vv[k][0] = v.x; vv[k][1] = v.y; vv[k][2] = v.z; vv[k][3] = v.w;
        }
        #pragma unroll
        for (int kc = 0; kc < 4; ++kc) {
            float4 pw = {vv[0][kc], vv[1][kc], vv[2][kc], vv[3][kc]};
            *reinterpret_cast<float4*>(&sxS[(c4 + kc) * SXS_LD + 4 * p4]) = pw;
        }
    }
    __syncthreads();

    const int lane = tid & 63, w = tid >> 6;
    const int i16 = lane & 15, g = lane >> 4;
    const int i0 = 16 * w + 4 * g;

    const int fbase[NS] = {0, 2, 4, 6, 9};
    const int ksn[NS]   = {2, 2, 2, 3, 4};
    const int RA[NS]    = {16, 16, 24, 40, 56};

    #pragma unroll
    for (int ct = 0; ct < 4; ++ct) {
        const int c = 16 * ct + i16;

        // ---- conv via MFMA: 13 k-steps over 5 sigmas ----
        f32x4 acc[NS];
        #pragma unroll
        for (int s = 0; s < NS; ++s) acc[s] = (f32x4){0.f, 0.f, 0.f, 0.f};
        #pragma unroll
        for (int s = 0; s < NS; ++s) {
            #pragma unroll
            for (int kk = 0; kk < ksn[s]; ++kk) {
                const bf16x8 A = *reinterpret_cast<const bf16x8*>(
                    afr + ((size_t)(fbase[s] + kk) * 64 + lane) * 8);
                const int tof = 16 * w - RA[s] + 32 * kk + RMX + 8 * g;
                const bf16x8 B = *reinterpret_cast<const bf16x8*>(&sxT[c * SXT_LD + tof]);
                acc[s] = __builtin_amdgcn_mfma_f32_16x16x32_bf16(A, B, acc[s], 0, 0, 0);
            }
        }

        // ---- causal stats: 20 f32 via 5 ds_read_b128 ----
        float f[20];
        const float* sp = &sxS[c * SXS_LD + i0];
        #pragma unroll
        for (int q = 0; q < 5; ++q)
            *reinterpret_cast<float4*>(&f[4 * q]) = *reinterpret_cast<const float4*>(sp + 4 * q);
        float s1 = 0.f, s2 = 0.f;
        #pragma unroll
        for (int q = 0; q < 16; ++q) { const float v = f[q]; s1 += v; s2 = fmaf(v, v, s2); }

        #pragma unroll
        for (int d = 0; d < 4; ++d) {
            const int tglob = t0 + i0 + d;
            const float eff = fminf((float)(tglob + 1), 16.0f);
            const float re = __fdividef(1.0f, eff + 1e-12f);
            const float mn = s1 * re;
            const float m2 = s2 * re;
            const float var = fmaxf(m2 - mn * mn, 0.f);
            const float z  = (f[15 + d] - mn) * rsqrtf(var + 1e-6f);
            const float lv = __logf(var + 1e-6f);

            const float y0 = acc[0][d], y1 = acc[1][d], y2 = acc[2][d],
                        y3 = acc[3][d], y4 = acc[4][d];
            float res;
            const bool fast = (!SLOW) && (tglob >= 15) && (fabsf(z) <= 3.9f)
                              && (lv >= -13.9f) && (lv <= 3.9f);
            if (fast) {
                const float fz = (z - ZMINF) * ZSCLF;
                const float fv = (lv - VMINF) * VSCLF;
                const int zi = (int)fz, vi = (int)fv;
                const float az = fz - (float)zi, av = fv - (float)vi;
                const int cidx = zi * NV + vi;
                const uint4 r0 = tb4[cidx];
                const uint4 r1 = tb4[cidx + NV];
                // v-interp then z-interp, all f32
                const float c00 = fmaf(av, hlo(r0.z) - hlo(r0.x), hlo(r0.x));
                const float c01 = fmaf(av, hhi(r0.z) - hhi(r0.x), hhi(r0.x));
                const float c02 = fmaf(av, hlo(r0.w) - hlo(r0.y), hlo(r0.y));
                const float c03 = fmaf(av, hhi(r0.w) - hhi(r0.y), hhi(r0.y));
                const float c10 = fmaf(av, hlo(r1.z) - hlo(r1.x), hlo(r1.x));
                const float c11 = fmaf(av, hhi(r1.z) - hhi(r1.x), hhi(r1.x));
                const float c12 = fmaf(av, hlo(r1.w) - hlo(r1.y), hlo(r1.y));
                const float c13 = fmaf(av, hhi(r1.w) - hhi(r1.y), hhi(r1.y));
                const float w0 = fmaf(az, c10 - c00, c00);
                const float w1 = fmaf(az, c11 - c01, c01);
                const float w2 = fmaf(az, c12 - c02, c02);
                const float w3 = fmaf(az, c13 - c03, c03);
                res = y4;
                res = fmaf(w0, y0 - y4, res);
                res = fmaf(w1, y1 - y4, res);
                res = fmaf(w2, y2 - y4, res);
                res = fmaf(w3, y3 - y4, res);
            } else {
                float wv[5];
                mlp_w(z, lv, W1, b1, W2, b2, wv);
                res = wv[0] * y0;
                res = fmaf(wv[1], y1, res);
                res = fmaf(wv[2], y2, res);
                res = fmaf(wv[3], y3, res);
                res = fmaf(wv[4], y4, res);
            }
            out[((size_t)b * NT + tglob) * NC + c] = res;

            if (d < 3) {   // slide the 16-window
                const float ad = f[16 + d], sb = f[d];
                s1 += ad - sb;
                s2 += ad * ad - sb * sb;
            }
        }
    }
}

extern "C" void kernel_launch(void* const* d_in, const int* in_sizes, int n_in,
                              void* d_out, int out_size, void* d_ws, size_t ws_size,
                              hipStream_t stream) {
    const float* x  = (const float*)d_in[0];
    const float* W1 = (const float*)d_in[1];
    const float* b1 = (const float*)d_in[2];
    const float* W2 = (const float*)d_in[3];
    const float* b2 = (const float*)d_in[4];
    float* out = (float*)d_out;
    unsigned short* afr = (unsigned short*)d_ws;              // 13312 B
    unsigned int* tbl = (unsigned int*)((char*)d_ws + FRAG_BYTES);

    init_frags_kernel<<<1, 256, 0, stream>>>(afr);
    if (ws_size >= WS_NEED) {
        build_table_kernel<<<(NZ * NV) / 256, 256, 0, stream>>>(W1, b1, W2, b2, tbl);
        fused3_kernel<false><<<NB * (NT / TTILE), 256, 0, stream>>>(
            x, W1, b1, W2, b2, afr, (const uint4*)tbl, out);
    } else {
        fused3_kernel<true><<<NB * (NT / TTILE), 256, 0, stream>>>(
            x, W1, b1, W2, b2, afr, (const uint4*)tbl, out);
    }
}